// Round 15
// baseline (2801.062 us; speedup 1.0000x reference)
//
#include <hip/hip_runtime.h>
#include <hip/hip_bf16.h>
#include <cmath>

// EncoderDecoder: S=49,B=64,DENC=512,DD=1800,DE=512,V=10000,T=20
// Round 15: revert GEMM to round-13 mfma_gemm9 (r14 counted-vmcnt regressed);
// fuse reduce_k(Q)+attn_u+softmax_ctx_pack into one attn_fused kernel
// (grid B): step goes 8 -> 6 dispatches, removing ~2 launch gaps/step.

namespace {

constexpr int S = 49, B = 64, DENC = 512, DD = 1800, DE = 512, V = 10000, T = 20;
constexpr int KC = DD + DE + DENC;   // 2824
constexpr int G4 = 4 * DD;           // 7200
constexpr int KCP = 2848;            // KC padded to %32
constexpr int DDP = 1824;            // DD padded to %32

typedef __attribute__((ext_vector_type(8))) short short8;
typedef __attribute__((ext_vector_type(4))) float f32x4;

__device__ inline float sigf(float x) { return 1.f / (1.f + expf(-x)); }

__device__ inline ushort f2bf_rne(float x) {
  unsigned u = __float_as_uint(x);
  unsigned r = (u + 0x7FFFu + ((u >> 16) & 1u)) >> 16;
  return (ushort)r;
}
__device__ inline void split1(float x, ushort& h, ushort& l) {
  h = f2bf_rne(x);
  float hf = __uint_as_float(((unsigned)h) << 16);
  l = f2bf_rne(x - hf);
}
__device__ inline void split8(float4 a, float4 b, short8& hi, short8& lo) {
  float v[8] = {a.x, a.y, a.z, a.w, b.x, b.y, b.z, b.w};
#pragma unroll
  for (int i = 0; i < 8; ++i) {
    ushort h, l; split1(v[i], h, l);
    hi[i] = (short)h; lo[i] = (short)l;
  }
}
// monotone float -> u32 key (preserves order for all finite floats)
__device__ inline unsigned fkey(float f) {
  unsigned u = __float_as_uint(f);
  return (u & 0x80000000u) ? ~u : (u | 0x80000000u);
}

// ---------------- h_avg = mean_s h[s,b,:] ----------------
__global__ __launch_bounds__(256) void hmean_kernel(const float* __restrict__ h,
                                                    float* __restrict__ h_avg) {
  int idx = blockIdx.x * 256 + threadIdx.x;
  if (idx >= B * DENC) return;
  float s = 0.f;
  for (int si = 0; si < S; ++si) s += h[(size_t)si * B * DENC + idx];
  h_avg[idx] = s * (1.0f / (float)S);
}

// ---------------- MFMA bf16x3 GEMM v9: async-LDS pipeline, 128n tile ------
// (verbatim round-13 version; proven)
__global__ __launch_bounds__(256) void mfma_gemm9(
    const ushort* __restrict__ Ahi, const ushort* __restrict__ Alo, int ldap,
    const float* __restrict__ Wa, int ldwa, int Ka,
    const float* __restrict__ Wb, int ldwb, int K,
    float* __restrict__ P, int M, int N, int KP, int kchunk) {
  __shared__ float lds[2][6144];  // 48 KB
  const int tid = threadIdx.x;
  const int lane = tid & 63;
  const int wv = tid >> 6;
  const int bn = blockIdx.x * 128;
  const int bm = blockIdx.y * 64;
  const int z = blockIdx.z;
  const int row = lane & 15;
  const int k_begin = z * kchunk;
  const int k_end = min(KP, k_begin + kchunk);

  auto stage = [&](int buf, int k0) {
#pragma unroll
    for (int q = 0; q < 4; ++q) {
      const int u = (wv * 4 + q) * 64 + lane;
      const int lr = u >> 3;
      const int pb = u & 7;
      int col = k0 + (pb ^ (lr & 7)) * 4;
      if (col >= K) col = 0;
      int grow = bn + lr;
      if (grow >= N) grow = N - 1;
      const float* src = (col < Ka) ? (Wa + (size_t)grow * ldwa + col)
                                    : (Wb + (size_t)grow * ldwb + (col - Ka));
      __builtin_amdgcn_global_load_lds(
          (const __attribute__((address_space(1))) unsigned int*)src,
          (__attribute__((address_space(3))) unsigned int*)
              &lds[buf][(wv * 4 + q) * 256 + lane * 4],
          16, 0, 0);
    }
    {
      const int u = wv * 64 + lane;
      const int lr = u >> 2;
      const int pb = u & 3;
      const int col = k0 + (pb ^ (lr & 3)) * 8;  // ushort index
      const ushort* sH = Ahi + (size_t)(bm + lr) * ldap + col;
      const ushort* sL = Alo + (size_t)(bm + lr) * ldap + col;
      __builtin_amdgcn_global_load_lds(
          (const __attribute__((address_space(1))) unsigned int*)sH,
          (__attribute__((address_space(3))) unsigned int*)
              &lds[buf][4096 + u * 4], 16, 0, 0);
      __builtin_amdgcn_global_load_lds(
          (const __attribute__((address_space(1))) unsigned int*)sL,
          (__attribute__((address_space(3))) unsigned int*)
              &lds[buf][5120 + u * 4], 16, 0, 0);
    }
  };

  f32x4 acc[2][4] = {};
  const int nsteps = (k_end > k_begin) ? ((k_end - k_begin) >> 5) : 0;
  if (nsteps) stage(0, k_begin);
  __syncthreads();

  for (int t = 0; t < nsteps; ++t) {
    const int cur = t & 1;
    if (t + 1 < nsteps) stage(cur ^ 1, k_begin + (t + 1) * 32);
    const int c0 = (lane >> 4) * 2;
    float4 w0a, w1a, w0b, w1b;
    {
      const int lrw = wv * 32 + row;
      const float* wb = &lds[cur][lrw * 32];
      w0a = *(const float4*)(wb + ((c0 ^ (lrw & 7)) * 4));
      w1a = *(const float4*)(wb + (((c0 + 1) ^ (lrw & 7)) * 4));
    }
    {
      const int lrw = wv * 32 + 16 + row;
      const float* wb = &lds[cur][lrw * 32];
      w0b = *(const float4*)(wb + ((c0 ^ (lrw & 7)) * 4));
      w1b = *(const float4*)(wb + (((c0 + 1) ^ (lrw & 7)) * 4));
    }
    short8 ah[4], al[4];
#pragma unroll
    for (int ms = 0; ms < 4; ++ms) {
      const int lra = ms * 16 + row;
      const int ca = lane >> 4;
      const int pc = (ca ^ (lra & 3)) * 4;
      ah[ms] = *(const short8*)(&lds[cur][4096 + lra * 16] + pc);
      al[ms] = *(const short8*)(&lds[cur][5120 + lra * 16] + pc);
    }
    short8 wh0, wl0, wh1, wl1;
    split8(w0a, w1a, wh0, wl0);
    split8(w0b, w1b, wh1, wl1);
#pragma unroll
    for (int ms = 0; ms < 4; ++ms) {
      acc[0][ms] = __builtin_amdgcn_mfma_f32_16x16x32_bf16(ah[ms], wh0, acc[0][ms], 0, 0, 0);
      acc[0][ms] = __builtin_amdgcn_mfma_f32_16x16x32_bf16(al[ms], wh0, acc[0][ms], 0, 0, 0);
      acc[0][ms] = __builtin_amdgcn_mfma_f32_16x16x32_bf16(ah[ms], wl0, acc[0][ms], 0, 0, 0);
      acc[1][ms] = __builtin_amdgcn_mfma_f32_16x16x32_bf16(ah[ms], wh1, acc[1][ms], 0, 0, 0);
      acc[1][ms] = __builtin_amdgcn_mfma_f32_16x16x32_bf16(al[ms], wh1, acc[1][ms], 0, 0, 0);
      acc[1][ms] = __builtin_amdgcn_mfma_f32_16x16x32_bf16(ah[ms], wl1, acc[1][ms], 0, 0, 0);
    }
    __syncthreads();
  }

  float* Pz = P + (size_t)z * ((size_t)M * N);
#pragma unroll
  for (int j = 0; j < 2; ++j) {
    const int n = bn + wv * 32 + j * 16 + row;
    if (n >= N) continue;
#pragma unroll
    for (int ms = 0; ms < 4; ++ms) {
      int r0 = bm + ms * 16 + (lane >> 4) * 4;
#pragma unroll
      for (int r = 0; r < 4; ++r)
        Pz[(size_t)(r0 + r) * N + n] = acc[j][ms][r];
    }
  }
}

// ---------------- reduce over split-K partials (+bias, +relu) ----------------
template <int ACT>
__global__ __launch_bounds__(256) void reduce_k(const float* __restrict__ P, int nz,
                                                int total4, size_t MN, int N,
                                                const float* __restrict__ bias,
                                                float* __restrict__ C) {
  int i4 = blockIdx.x * 256 + threadIdx.x;
  if (i4 >= total4) return;
  size_t idx = (size_t)i4 * 4;
  float4 s = *(const float4*)(P + idx);
  for (int zz = 1; zz < nz; ++zz) {
    float4 t = *(const float4*)(P + (size_t)zz * MN + idx);
    s.x += t.x; s.y += t.y; s.z += t.z; s.w += t.w;
  }
  if (bias) {
    int nn = (int)(idx % (size_t)N);
    s.x += bias[nn]; s.y += bias[nn + 1]; s.z += bias[nn + 2]; s.w += bias[nn + 3];
  }
  if (ACT == 1) {
    s.x = fmaxf(s.x, 0.f); s.y = fmaxf(s.y, 0.f);
    s.z = fmaxf(s.z, 0.f); s.w = fmaxf(s.w, 0.f);
  }
  *(float4*)(C + idx) = s;
}

// ---------------- logits: z-reduce + bias + store + fused argmax ------------
__global__ __launch_bounds__(256) void reduce_lg(const float* __restrict__ P, int nz,
                                                 const float* __restrict__ bias,
                                                 float* __restrict__ C,
                                                 unsigned long long* __restrict__ amax) {
  const int seg = blockIdx.x, b = blockIdx.y;
  const int tid = threadIdx.x;
  const size_t MN = (size_t)B * V;
  unsigned long long best = 0;
  for (int i = tid; i < 250; i += 256) {
    const int n = seg * 1000 + i * 4;
    const size_t idx = (size_t)b * V + n;
    float4 s = *(const float4*)(P + idx);
    for (int zz = 1; zz < nz; ++zz) {
      float4 t = *(const float4*)(P + (size_t)zz * MN + idx);
      s.x += t.x; s.y += t.y; s.z += t.z; s.w += t.w;
    }
    s.x += bias[n]; s.y += bias[n + 1]; s.z += bias[n + 2]; s.w += bias[n + 3];
    *(float4*)(C + idx) = s;
    float v[4] = {s.x, s.y, s.z, s.w};
#pragma unroll
    for (int j = 0; j < 4; ++j) {
      unsigned long long k =
          ((unsigned long long)fkey(v[j]) << 32) | (unsigned)(~(n + j));
      if (k > best) best = k;
    }
  }
  for (int off = 32; off; off >>= 1) {
    unsigned long long o = __shfl_xor(best, off);
    if (o > best) best = o;
  }
  __shared__ unsigned long long red[4];
  if ((tid & 63) == 0) red[tid >> 6] = best;
  __syncthreads();
  if (tid == 0) {
    for (int w = 1; w < 4; ++w)
      if (red[w] > best) best = red[w];
    atomicMax(&amax[b], best);
  }
}

// ---------------- row-per-block split: fp32 rows -> bf16 hi/lo planes -------
__global__ __launch_bounds__(256) void split_row(
    const float* __restrict__ Wa, int ldwa, int Ka,
    int KP, ushort* __restrict__ hi, ushort* __restrict__ lo) {
  const int r = blockIdx.x;
  const float* ra = Wa + (size_t)r * ldwa;
  ushort* hr = hi + (size_t)r * KP;
  ushort* lr = lo + (size_t)r * KP;
  for (int k = threadIdx.x * 4; k < KP; k += 1024) {
    float4 v = {0.f, 0.f, 0.f, 0.f};
    if (k + 4 <= Ka) v = *(const float4*)(ra + k);
    ushort h0, l0, h1, l1, h2, l2, h3, l3;
    split1(v.x, h0, l0); split1(v.y, h1, l1);
    split1(v.z, h2, l2); split1(v.w, h3, l3);
    ushort4 hv = {h0, h1, h2, h3}, lv = {l0, l1, l2, l3};
    *(ushort4*)(hr + k) = hv;
    *(ushort4*)(lr + k) = lv;
  }
}

// ---------------- fused: Q z-reduce + u + softmax + beta + ctx + packing ----
// grid (B). Thread t owns k-float4 indices {t, t+256} of [0,450).
__global__ __launch_bounds__(256) void attn_fused(
    const float* __restrict__ P, int nz,
    const float* __restrict__ Hproj,
    const float* __restrict__ w2, const float* __restrict__ b2,
    const float* __restrict__ h, const float* __restrict__ ht,
    const float* __restrict__ beta_w, const float* __restrict__ beta_b,
    const float* __restrict__ emb, const int* __restrict__ Et,
    const unsigned long long* __restrict__ amax,
    ushort* __restrict__ xcat_hi, ushort* __restrict__ xcat_lo,
    ushort* __restrict__ cat2_hi, ushort* __restrict__ cat2_lo) {
  const int b = blockIdx.x, tid = threadIdx.x;
  const int wv = tid >> 6;
  __shared__ float redw[S * 4];
  __shared__ float red_b[4];
  __shared__ float u_sh[S];
  __shared__ float a_sh[S];

  const int f0 = tid, f1 = tid + 256;
  const bool v1 = (f1 < DD / 4);

  // Q[b] = sum_z partials (same element-wise z order as reduce_k)
  float4 q0 = {0.f, 0.f, 0.f, 0.f}, q1 = {0.f, 0.f, 0.f, 0.f};
  for (int z = 0; z < nz; ++z) {
    const float* pr = P + (size_t)z * ((size_t)B * DD) + (size_t)b * DD;
    float4 t0 = *(const float4*)(pr + f0 * 4);
    q0.x += t0.x; q0.y += t0.y; q0.z += t0.z; q0.w += t0.w;
    if (v1) {
      float4 t1 = *(const float4*)(pr + f1 * 4);
      q1.x += t1.x; q1.y += t1.y; q1.z += t1.z; q1.w += t1.w;
    }
  }
  float4 w0 = *(const float4*)(w2 + f0 * 4);
  float4 w1 = {0.f, 0.f, 0.f, 0.f};
  if (v1) w1 = *(const float4*)(w2 + f1 * 4);

  // beta partial (same {t, t+256} ownership as before)
  {
    const float* hr = ht + (size_t)b * DD;
    float4 x0 = *(const float4*)(hr + f0 * 4);
    float4 bw0 = *(const float4*)(beta_w + f0 * 4);
    float p = x0.x * bw0.x + x0.y * bw0.y + x0.z * bw0.z + x0.w * bw0.w;
    if (v1) {
      float4 x1 = *(const float4*)(hr + f1 * 4);
      float4 bw1 = *(const float4*)(beta_w + f1 * 4);
      p += x1.x * bw1.x + x1.y * bw1.y + x1.z * bw1.z + x1.w * bw1.w;
    }
    for (int off = 32; off; off >>= 1) p += __shfl_xor(p, off);
    if ((tid & 63) == 0) red_b[wv] = p;
  }

  // u[s] partials
  for (int s = 0; s < S; ++s) {
    const float* hp = Hproj + ((size_t)s * B + b) * DD;
    float4 a0 = *(const float4*)(hp + f0 * 4);
    float p = fmaxf(q0.x + a0.x, 0.f) * w0.x + fmaxf(q0.y + a0.y, 0.f) * w0.y +
              fmaxf(q0.z + a0.z, 0.f) * w0.z + fmaxf(q0.w + a0.w, 0.f) * w0.w;
    if (v1) {
      float4 a1 = *(const float4*)(hp + f1 * 4);
      p += fmaxf(q1.x + a1.x, 0.f) * w1.x + fmaxf(q1.y + a1.y, 0.f) * w1.y +
           fmaxf(q1.z + a1.z, 0.f) * w1.z + fmaxf(q1.w + a1.w, 0.f) * w1.w;
    }
    for (int off = 32; off; off >>= 1) p += __shfl_xor(p, off);
    if ((tid & 63) == 0) redw[s * 4 + wv] = p;
  }
  __syncthreads();
  float beta = sigf(red_b[0] + red_b[1] + red_b[2] + red_b[3] + beta_b[0]);
  if (tid < S)
    u_sh[tid] = redw[tid * 4] + redw[tid * 4 + 1] + redw[tid * 4 + 2] +
                redw[tid * 4 + 3] + b2[0];
  __syncthreads();
  if (tid < S) {
    float m = -INFINITY;
    for (int s = 0; s < S; ++s) m = fmaxf(m, u_sh[s]);
    float ssum = 0.f;
    for (int s = 0; s < S; ++s) ssum += expf(u_sh[s] - m);
    a_sh[tid] = expf(u_sh[tid] - m) / ssum;
  }
  __syncthreads();

  // ctx + packing
  const size_t xb = (size_t)b * KCP;
  for (int e0 = tid; e0 < DENC; e0 += 256) {
    float c = 0.f;
    for (int si = 0; si < S; ++si) c += a_sh[si] * h[((size_t)si * B + b) * DENC + e0];
    c *= beta;
    ushort hh, ll; split1(c, hh, ll);
    xcat_hi[xb + DE + e0] = hh;      xcat_lo[xb + DE + e0] = ll;
    cat2_hi[xb + DD + DE + e0] = hh; cat2_lo[xb + DD + DE + e0] = ll;
  }
  int et = Et[b];
  int pt = (int)(~(unsigned)(amax[b] & 0xFFFFFFFFull));  // decoded argmax
  for (int e0 = tid; e0 < DE; e0 += 256) {
    ushort hh, ll;
    split1(emb[(size_t)et * DE + e0], hh, ll);
    xcat_hi[xb + e0] = hh; xcat_lo[xb + e0] = ll;
    split1(emb[(size_t)pt * DE + e0], hh, ll);
    cat2_hi[xb + DD + e0] = hh; cat2_lo[xb + DD + e0] = ll;
  }
  for (int j = tid; j < DD; j += 256) {
    ushort hh, ll; split1(ht[(size_t)b * DD + j], hh, ll);
    xcat_hi[xb + DE + DENC + j] = hh; xcat_lo[xb + DE + DENC + j] = ll;
  }
  if (tid < KCP - KC) {
    xcat_hi[xb + KC + tid] = 0; xcat_lo[xb + KC + tid] = 0;
    cat2_hi[xb + KC + tid] = 0; cat2_lo[xb + KC + tid] = 0;
  }
}

// ---------------- LSTM: reduce gates partials + update + bf16 splits --------
__global__ __launch_bounds__(256) void lstm_fused(
    const float* __restrict__ P, int nz, const float* __restrict__ b_ih,
    const float* __restrict__ b_hh, float* __restrict__ ct, float* __restrict__ ht,
    ushort* __restrict__ cat2_hi, ushort* __restrict__ cat2_lo,
    ushort* __restrict__ ht_hi, ushort* __restrict__ ht_lo,
    unsigned long long* __restrict__ amax) {
  int idx = blockIdx.x * 256 + threadIdx.x;
  if (idx < B) amax[idx] = 0ull;
  if (idx >= B * DD) return;
  int b = idx / DD, d = idx % DD;
  const size_t MN = (size_t)B * G4;
  float g0 = 0.f, g1 = 0.f, g2 = 0.f, g3 = 0.f;
  for (int zz = 0; zz < nz; ++zz) {
    const float* g = P + (size_t)zz * MN + (size_t)b * G4;
    g0 += g[d]; g1 += g[DD + d]; g2 += g[2 * DD + d]; g3 += g[3 * DD + d];
  }
  g0 += b_ih[d] + b_hh[d];
  g1 += b_ih[DD + d] + b_hh[DD + d];
  g2 += b_ih[2 * DD + d] + b_hh[2 * DD + d];
  g3 += b_ih[3 * DD + d] + b_hh[3 * DD + d];
  float c = sigf(g1) * ct[idx] + sigf(g0) * tanhf(g2);
  float hn = sigf(g3) * tanhf(c);
  ct[idx] = c;
  ht[idx] = hn;
  ushort hh, ll; split1(hn, hh, ll);
  cat2_hi[(size_t)b * KCP + d] = hh; cat2_lo[(size_t)b * KCP + d] = ll;
  ht_hi[(size_t)b * DDP + d] = hh;   ht_lo[(size_t)b * DDP + d] = ll;
  if (d < DDP - DD) {
    ht_hi[(size_t)b * DDP + DD + d] = 0; ht_lo[(size_t)b * DDP + DD + d] = 0;
  }
}

// init: low32 = ~0 -> decodes to token 0
__global__ void init_amax(unsigned long long* amax) {
  if (threadIdx.x < B) amax[threadIdx.x] = 0x00000000FFFFFFFFull;
}

// ---- ws layout (float offsets): fp32 region | PBUF | ushort activations ----
constexpr size_t OFF_HAVG  = 0;
constexpr size_t OFF_TMP   = OFF_HAVG + 32768;
constexpr size_t OFF_HT    = OFF_TMP + 115200;
constexpr size_t OFF_CT    = OFF_HT + 115200;
constexpr size_t OFF_HPROJ = OFF_CT + 115200;         // 3136*1800
constexpr size_t OFF_Q     = OFF_HPROJ + 5644800;
constexpr size_t OFF_U     = OFF_Q + 115200;
constexpr size_t OFF_TOK   = OFF_U + 3200;            // 64 u64 = 128 floats
constexpr size_t OFF_PBUF  = OFF_TOK + 128;
constexpr size_t PBUF_F    = 6400000;                 // z=10 * B*V
constexpr size_t OFF_USH   = OFF_PBUF + PBUF_F;

// ushort offsets within ushort area (~58.5 MB total, proven to fit)
constexpr size_t U_HT_HI  = 0;
constexpr size_t U_HT_LO  = U_HT_HI + (size_t)B * DDP;
constexpr size_t U_XC_HI  = U_HT_LO + (size_t)B * DDP;
constexpr size_t U_XC_LO  = U_XC_HI + (size_t)B * KCP;
constexpr size_t U_C2_HI  = U_XC_LO + (size_t)B * KCP;
constexpr size_t U_C2_LO  = U_C2_HI + (size_t)B * KCP;
constexpr size_t U_H_HI   = U_C2_LO + (size_t)B * KCP;
constexpr size_t U_H_LO   = U_H_HI + (size_t)(S * B) * DENC;

}  // namespace

extern "C" void kernel_launch(void* const* d_in, const int* in_sizes, int n_in,
                              void* d_out, int out_size, void* d_ws, size_t ws_size,
                              hipStream_t stream) {
  const float* h       = (const float*)d_in[0];
  const int*   E       = (const int*)d_in[1];
  const float* emb     = (const float*)d_in[2];
  const float* attn_W1 = (const float*)d_in[3];
  const float* attn_b1 = (const float*)d_in[4];
  const float* attn_w2 = (const float*)d_in[5];
  const float* attn_b2 = (const float*)d_in[6];
  const float* beta_w  = (const float*)d_in[7];
  const float* beta_b  = (const float*)d_in[8];
  const float* W_ih    = (const float*)d_in[9];
  const float* W_hh    = (const float*)d_in[10];
  const float* b_ih    = (const float*)d_in[11];
  const float* b_hh    = (const float*)d_in[12];
  const float* out_W   = (const float*)d_in[13];
  const float* out_b   = (const float*)d_in[14];
  const float* ih_W1   = (const float*)d_in[15];
  const float* ih_b1   = (const float*)d_in[16];
  const float* ih_W2   = (const float*)d_in[17];
  const float* ih_b2   = (const float*)d_in[18];
  const float* ic_W1   = (const float*)d_in[19];
  const float* ic_b1   = (const float*)d_in[20];
  const float* ic_W2   = (const float*)d_in[21];
  const float* ic_b2   = (const float*)d_in[22];

  float* ws    = (float*)d_ws;
  float* havg  = ws + OFF_HAVG;
  float* tmp   = ws + OFF_TMP;
  float* ht    = ws + OFF_HT;
  float* ct    = ws + OFF_CT;
  float* Hproj = ws + OFF_HPROJ;
  unsigned long long* amax = (unsigned long long*)(ws + OFF_TOK);
  float* PBUF  = ws + OFF_PBUF;
  ushort* bfb  = (ushort*)(ws + OFF_USH);
  ushort* ht_hi = bfb + U_HT_HI;
  ushort* ht_lo = bfb + U_HT_LO;
  ushort* xc_hi = bfb + U_XC_HI;
  ushort* xc_lo = bfb + U_XC_LO;
  ushort* c2_hi = bfb + U_C2_HI;
  ushort* c2_lo = bfb + U_C2_LO;
  ushort* h_hi  = bfb + U_H_HI;
  ushort* h_lo  = bfb + U_H_LO;
  float* out   = (float*)d_out;

  // prologue scratch (reuses step-loop activation areas before first step)
  ushort* hv_hi = xc_hi;   // havg planes, KP=512
  ushort* hv_lo = xc_lo;
  ushort* t_hi  = c2_hi;   // tmp planes, KP=1824
  ushort* t_lo  = c2_lo;

  auto cdiv = [](int a, int b) { return (a + b - 1) / b; };
  const int BIGK = 1 << 28;

  // ---- prologue ----
  hmean_kernel<<<cdiv(B * DENC, 256), 256, 0, stream>>>(h, havg);
  split_row<<<B, 256, 0, stream>>>(havg, DENC, DENC, DENC, hv_hi, hv_lo);
  // h0: tmp = relu(havg @ ih_W1.T + b1); ht = tmp @ ih_W2.T + b2
  mfma_gemm9<<<dim3(cdiv(DD, 128), 1, 4), 256, 0, stream>>>(
      hv_hi, hv_lo, DENC, ih_W1, DENC, BIGK, ih_W1, DENC, DENC,
      PBUF, B, DD, DENC, 128);
  reduce_k<1><<<cdiv(B * DD / 4, 256), 256, 0, stream>>>(
      PBUF, 4, B * DD / 4, (size_t)B * DD, DD, ih_b1, tmp);
  split_row<<<B, 256, 0, stream>>>(tmp, DD, DD, DDP, t_hi, t_lo);
  mfma_gemm9<<<dim3(cdiv(DD, 128), 1, 12), 256, 0, stream>>>(
      t_hi, t_lo, DDP, ih_W2, DD, BIGK, ih_W2, DD, DD,
      PBUF, B, DD, DDP, 160);
  reduce_k<0><<<cdiv(B * DD / 4, 256), 256, 0, stream>>>(
      PBUF, 12, B * DD / 4, (size_t)B * DD, DD, ih_b2, ht);
  // c0
  mfma_gemm9<<<dim3(cdiv(DD, 128), 1, 4), 256, 0, stream>>>(
      hv_hi, hv_lo, DENC, ic_W1, DENC, BIGK, ic_W1, DENC, DENC,
      PBUF, B, DD, DENC, 128);
  reduce_k<1><<<cdiv(B * DD / 4, 256), 256, 0, stream>>>(
      PBUF, 4, B * DD / 4, (size_t)B * DD, DD, ic_b1, tmp);
  split_row<<<B, 256, 0, stream>>>(tmp, DD, DD, DDP, t_hi, t_lo);
  mfma_gemm9<<<dim3(cdiv(DD, 128), 1, 12), 256, 0, stream>>>(
      t_hi, t_lo, DDP, ic_W2, DD, BIGK, ic_W2, DD, DD,
      PBUF, B, DD, DDP, 160);
  reduce_k<0><<<cdiv(B * DD / 4, 256), 256, 0, stream>>>(
      PBUF, 12, B * DD / 4, (size_t)B * DD, DD, ic_b2, ct);
  // splits for step loop
  split_row<<<B, 256, 0, stream>>>(ht, DD, DD, DDP, ht_hi, ht_lo);
  split_row<<<S * B, 256, 0, stream>>>(h, DENC, DENC, DENC, h_hi, h_lo);
  // Hproj = h @ W1h.T + attn_b1  (z=1, kchunk=512)
  mfma_gemm9<<<dim3(cdiv(DD, 128), S * B / 64, 1), 256, 0, stream>>>(
      h_hi, h_lo, DENC, attn_W1 + DD, DD + DENC, BIGK, attn_W1 + DD,
      DD + DENC, DENC, Hproj, S * B, DD, DENC, 512);
  reduce_k<0><<<cdiv(S * B * DD / 4, 256), 256, 0, stream>>>(
      Hproj, 1, S * B * DD / 4, (size_t)S * B * DD, DD, attn_b1, Hproj);
  init_amax<<<1, 64, 0, stream>>>(amax);

  // ---- decode steps (6 dispatches each) ----
  for (int t = 0; t < T - 1; ++t) {
    // Q = ht @ W1q.T  (z=12, kchunk=160) -> PBUF partials
    mfma_gemm9<<<dim3(cdiv(DD, 128), 1, 12), 256, 0, stream>>>(
        ht_hi, ht_lo, DDP, attn_W1, DD + DENC, BIGK, attn_W1, DD + DENC, DD,
        PBUF, B, DD, DDP, 160);
    // fused: Q-reduce + u + softmax + beta + ctx + packing
    attn_fused<<<B, 256, 0, stream>>>(
        PBUF, 12, Hproj, attn_w2, attn_b2, h, ht, beta_w, beta_b, emb,
        E + (size_t)t * B, amax, xc_hi, xc_lo, c2_hi, c2_lo);
    // gates = xcat @ [W_ih | W_hh].T  (z=12, kchunk=256)
    mfma_gemm9<<<dim3(cdiv(G4, 128), 1, 12), 256, 0, stream>>>(
        xc_hi, xc_lo, KCP, W_ih, DE + DENC, DE + DENC, W_hh, DD, KC,
        PBUF, B, G4, KCP, 256);
    lstm_fused<<<cdiv(B * DD, 256), 256, 0, stream>>>(
        PBUF, 12, b_ih, b_hh, ct, ht, c2_hi, c2_lo, ht_hi, ht_lo, amax);
    // logits = cat2 @ out_W.T  (z=10, kchunk=288) -> d_out[t], fused argmax
    float* logits_t = out + (size_t)t * B * V;
    mfma_gemm9<<<dim3(cdiv(V, 128), 1, 10), 256, 0, stream>>>(
        c2_hi, c2_lo, KCP, out_W, KC, BIGK, out_W, KC, KC,
        PBUF, B, V, KCP, 288);
    reduce_lg<<<dim3(10, B), 256, 0, stream>>>(PBUF, 10, out_b, logits_t, amax);
  }
  (void)in_sizes; (void)n_in; (void)out_size; (void)ws_size;
}

// Round 16
// 2080.402 us; speedup vs baseline: 1.3464x; 1.3464x over previous
//
#include <hip/hip_runtime.h>
#include <hip/hip_bf16.h>
#include <cmath>

// EncoderDecoder: S=49,B=64,DENC=512,DD=1800,DE=512,V=10000,T=20
// Round 16: revert to round-13 (proven best, 2088us) + fold Hproj bias into
// mfma_gemm9 epilogue (z=1 path), dropping the 5.6M-element reduce_k.

namespace {

constexpr int S = 49, B = 64, DENC = 512, DD = 1800, DE = 512, V = 10000, T = 20;
constexpr int KC = DD + DE + DENC;   // 2824
constexpr int G4 = 4 * DD;           // 7200
constexpr int KCP = 2848;            // KC padded to %32
constexpr int DDP = 1824;            // DD padded to %32

typedef __attribute__((ext_vector_type(8))) short short8;
typedef __attribute__((ext_vector_type(4))) float f32x4;

__device__ inline float sigf(float x) { return 1.f / (1.f + expf(-x)); }

__device__ inline ushort f2bf_rne(float x) {
  unsigned u = __float_as_uint(x);
  unsigned r = (u + 0x7FFFu + ((u >> 16) & 1u)) >> 16;
  return (ushort)r;
}
__device__ inline void split1(float x, ushort& h, ushort& l) {
  h = f2bf_rne(x);
  float hf = __uint_as_float(((unsigned)h) << 16);
  l = f2bf_rne(x - hf);
}
__device__ inline void split8(float4 a, float4 b, short8& hi, short8& lo) {
  float v[8] = {a.x, a.y, a.z, a.w, b.x, b.y, b.z, b.w};
#pragma unroll
  for (int i = 0; i < 8; ++i) {
    ushort h, l; split1(v[i], h, l);
    hi[i] = (short)h; lo[i] = (short)l;
  }
}
// monotone float -> u32 key (preserves order for all finite floats)
__device__ inline unsigned fkey(float f) {
  unsigned u = __float_as_uint(f);
  return (u & 0x80000000u) ? ~u : (u | 0x80000000u);
}

// ---------------- h_avg = mean_s h[s,b,:] ----------------
__global__ __launch_bounds__(256) void hmean_kernel(const float* __restrict__ h,
                                                    float* __restrict__ h_avg) {
  int idx = blockIdx.x * 256 + threadIdx.x;
  if (idx >= B * DENC) return;
  float s = 0.f;
  for (int si = 0; si < S; ++si) s += h[(size_t)si * B * DENC + idx];
  h_avg[idx] = s * (1.0f / (float)S);
}

// ---------------- MFMA bf16x3 GEMM v9: async-LDS pipeline, 128n tile ------
// Round-13 version + optional epilogue bias (use only with gridDim.z == 1).
__global__ __launch_bounds__(256) void mfma_gemm9(
    const ushort* __restrict__ Ahi, const ushort* __restrict__ Alo, int ldap,
    const float* __restrict__ Wa, int ldwa, int Ka,
    const float* __restrict__ Wb, int ldwb, int K,
    float* __restrict__ P, int M, int N, int KP, int kchunk,
    const float* __restrict__ ebias) {
  __shared__ float lds[2][6144];  // 48 KB
  const int tid = threadIdx.x;
  const int lane = tid & 63;
  const int wv = tid >> 6;
  const int bn = blockIdx.x * 128;
  const int bm = blockIdx.y * 64;
  const int z = blockIdx.z;
  const int row = lane & 15;
  const int k_begin = z * kchunk;
  const int k_end = min(KP, k_begin + kchunk);

  auto stage = [&](int buf, int k0) {
#pragma unroll
    for (int q = 0; q < 4; ++q) {
      const int u = (wv * 4 + q) * 64 + lane;
      const int lr = u >> 3;
      const int pb = u & 7;
      int col = k0 + (pb ^ (lr & 7)) * 4;
      if (col >= K) col = 0;
      int grow = bn + lr;
      if (grow >= N) grow = N - 1;
      const float* src = (col < Ka) ? (Wa + (size_t)grow * ldwa + col)
                                    : (Wb + (size_t)grow * ldwb + (col - Ka));
      __builtin_amdgcn_global_load_lds(
          (const __attribute__((address_space(1))) unsigned int*)src,
          (__attribute__((address_space(3))) unsigned int*)
              &lds[buf][(wv * 4 + q) * 256 + lane * 4],
          16, 0, 0);
    }
    {
      const int u = wv * 64 + lane;
      const int lr = u >> 2;
      const int pb = u & 3;
      const int col = k0 + (pb ^ (lr & 3)) * 8;  // ushort index
      const ushort* sH = Ahi + (size_t)(bm + lr) * ldap + col;
      const ushort* sL = Alo + (size_t)(bm + lr) * ldap + col;
      __builtin_amdgcn_global_load_lds(
          (const __attribute__((address_space(1))) unsigned int*)sH,
          (__attribute__((address_space(3))) unsigned int*)
              &lds[buf][4096 + u * 4], 16, 0, 0);
      __builtin_amdgcn_global_load_lds(
          (const __attribute__((address_space(1))) unsigned int*)sL,
          (__attribute__((address_space(3))) unsigned int*)
              &lds[buf][5120 + u * 4], 16, 0, 0);
    }
  };

  f32x4 acc[2][4] = {};
  const int nsteps = (k_end > k_begin) ? ((k_end - k_begin) >> 5) : 0;
  if (nsteps) stage(0, k_begin);
  __syncthreads();

  for (int t = 0; t < nsteps; ++t) {
    const int cur = t & 1;
    if (t + 1 < nsteps) stage(cur ^ 1, k_begin + (t + 1) * 32);
    const int c0 = (lane >> 4) * 2;
    float4 w0a, w1a, w0b, w1b;
    {
      const int lrw = wv * 32 + row;
      const float* wb = &lds[cur][lrw * 32];
      w0a = *(const float4*)(wb + ((c0 ^ (lrw & 7)) * 4));
      w1a = *(const float4*)(wb + (((c0 + 1) ^ (lrw & 7)) * 4));
    }
    {
      const int lrw = wv * 32 + 16 + row;
      const float* wb = &lds[cur][lrw * 32];
      w0b = *(const float4*)(wb + ((c0 ^ (lrw & 7)) * 4));
      w1b = *(const float4*)(wb + (((c0 + 1) ^ (lrw & 7)) * 4));
    }
    short8 ah[4], al[4];
#pragma unroll
    for (int ms = 0; ms < 4; ++ms) {
      const int lra = ms * 16 + row;
      const int ca = lane >> 4;
      const int pc = (ca ^ (lra & 3)) * 4;
      ah[ms] = *(const short8*)(&lds[cur][4096 + lra * 16] + pc);
      al[ms] = *(const short8*)(&lds[cur][5120 + lra * 16] + pc);
    }
    short8 wh0, wl0, wh1, wl1;
    split8(w0a, w1a, wh0, wl0);
    split8(w0b, w1b, wh1, wl1);
#pragma unroll
    for (int ms = 0; ms < 4; ++ms) {
      acc[0][ms] = __builtin_amdgcn_mfma_f32_16x16x32_bf16(ah[ms], wh0, acc[0][ms], 0, 0, 0);
      acc[0][ms] = __builtin_amdgcn_mfma_f32_16x16x32_bf16(al[ms], wh0, acc[0][ms], 0, 0, 0);
      acc[0][ms] = __builtin_amdgcn_mfma_f32_16x16x32_bf16(ah[ms], wl0, acc[0][ms], 0, 0, 0);
      acc[1][ms] = __builtin_amdgcn_mfma_f32_16x16x32_bf16(ah[ms], wh1, acc[1][ms], 0, 0, 0);
      acc[1][ms] = __builtin_amdgcn_mfma_f32_16x16x32_bf16(al[ms], wh1, acc[1][ms], 0, 0, 0);
      acc[1][ms] = __builtin_amdgcn_mfma_f32_16x16x32_bf16(ah[ms], wl1, acc[1][ms], 0, 0, 0);
    }
    __syncthreads();
  }

  float* Pz = P + (size_t)z * ((size_t)M * N);
#pragma unroll
  for (int j = 0; j < 2; ++j) {
    const int n = bn + wv * 32 + j * 16 + row;
    if (n >= N) continue;
    const float bv = ebias ? ebias[n] : 0.f;
#pragma unroll
    for (int ms = 0; ms < 4; ++ms) {
      int r0 = bm + ms * 16 + (lane >> 4) * 4;
#pragma unroll
      for (int r = 0; r < 4; ++r)
        Pz[(size_t)(r0 + r) * N + n] = acc[j][ms][r] + bv;
    }
  }
}

// ---------------- reduce over split-K partials (+bias, +relu) ----------------
template <int ACT>
__global__ __launch_bounds__(256) void reduce_k(const float* __restrict__ P, int nz,
                                                int total4, size_t MN, int N,
                                                const float* __restrict__ bias,
                                                float* __restrict__ C) {
  int i4 = blockIdx.x * 256 + threadIdx.x;
  if (i4 >= total4) return;
  size_t idx = (size_t)i4 * 4;
  float4 s = *(const float4*)(P + idx);
  for (int zz = 1; zz < nz; ++zz) {
    float4 t = *(const float4*)(P + (size_t)zz * MN + idx);
    s.x += t.x; s.y += t.y; s.z += t.z; s.w += t.w;
  }
  if (bias) {
    int nn = (int)(idx % (size_t)N);
    s.x += bias[nn]; s.y += bias[nn + 1]; s.z += bias[nn + 2]; s.w += bias[nn + 3];
  }
  if (ACT == 1) {
    s.x = fmaxf(s.x, 0.f); s.y = fmaxf(s.y, 0.f);
    s.z = fmaxf(s.z, 0.f); s.w = fmaxf(s.w, 0.f);
  }
  *(float4*)(C + idx) = s;
}

// ---------------- logits: z-reduce + bias + store + fused argmax ------------
__global__ __launch_bounds__(256) void reduce_lg(const float* __restrict__ P, int nz,
                                                 const float* __restrict__ bias,
                                                 float* __restrict__ C,
                                                 unsigned long long* __restrict__ amax) {
  const int seg = blockIdx.x, b = blockIdx.y;
  const int tid = threadIdx.x;
  const size_t MN = (size_t)B * V;
  unsigned long long best = 0;
  for (int i = tid; i < 250; i += 256) {
    const int n = seg * 1000 + i * 4;
    const size_t idx = (size_t)b * V + n;
    float4 s = *(const float4*)(P + idx);
    for (int zz = 1; zz < nz; ++zz) {
      float4 t = *(const float4*)(P + (size_t)zz * MN + idx);
      s.x += t.x; s.y += t.y; s.z += t.z; s.w += t.w;
    }
    s.x += bias[n]; s.y += bias[n + 1]; s.z += bias[n + 2]; s.w += bias[n + 3];
    *(float4*)(C + idx) = s;
    float v[4] = {s.x, s.y, s.z, s.w};
#pragma unroll
    for (int j = 0; j < 4; ++j) {
      unsigned long long k =
          ((unsigned long long)fkey(v[j]) << 32) | (unsigned)(~(n + j));
      if (k > best) best = k;
    }
  }
  for (int off = 32; off; off >>= 1) {
    unsigned long long o = __shfl_xor(best, off);
    if (o > best) best = o;
  }
  __shared__ unsigned long long red[4];
  if ((tid & 63) == 0) red[tid >> 6] = best;
  __syncthreads();
  if (tid == 0) {
    for (int w = 1; w < 4; ++w)
      if (red[w] > best) best = red[w];
    atomicMax(&amax[b], best);
  }
}

// ---------------- row-per-block split: fp32 rows -> bf16 hi/lo planes -------
__global__ __launch_bounds__(256) void split_row(
    const float* __restrict__ Wa, int ldwa, int Ka,
    int KP, ushort* __restrict__ hi, ushort* __restrict__ lo) {
  const int r = blockIdx.x;
  const float* ra = Wa + (size_t)r * ldwa;
  ushort* hr = hi + (size_t)r * KP;
  ushort* lr = lo + (size_t)r * KP;
  for (int k = threadIdx.x * 4; k < KP; k += 1024) {
    float4 v = {0.f, 0.f, 0.f, 0.f};
    if (k + 4 <= Ka) v = *(const float4*)(ra + k);
    ushort h0, l0, h1, l1, h2, l2, h3, l3;
    split1(v.x, h0, l0); split1(v.y, h1, l1);
    split1(v.z, h2, l2); split1(v.w, h3, l3);
    ushort4 hv = {h0, h1, h2, h3}, lv = {l0, l1, l2, l3};
    *(ushort4*)(hr + k) = hv;
    *(ushort4*)(lr + k) = lv;
  }
}

// ---------------- u[s,b] = relu(Q[b,:] + Hproj[s,b,:]) . w2 + b2 ----------------
__global__ __launch_bounds__(256) void attn_u_kernel(const float* __restrict__ Q,
                                                     const float* __restrict__ Hproj,
                                                     const float* __restrict__ w2,
                                                     const float* __restrict__ b2,
                                                     float* __restrict__ u) {
  int s = blockIdx.x, b = blockIdx.y;
  const float4* q4 = (const float4*)(Q + (size_t)b * DD);
  const float4* h4 = (const float4*)(Hproj + ((size_t)s * B + b) * DD);
  const float4* w4 = (const float4*)w2;
  float acc = 0.f;
  for (int i = threadIdx.x; i < DD / 4; i += 256) {
    float4 q = q4[i], hh = h4[i], w = w4[i];
    acc += fmaxf(q.x + hh.x, 0.f) * w.x + fmaxf(q.y + hh.y, 0.f) * w.y +
           fmaxf(q.z + hh.z, 0.f) * w.z + fmaxf(q.w + hh.w, 0.f) * w.w;
  }
  for (int off = 32; off; off >>= 1) acc += __shfl_xor(acc, off);
  __shared__ float red[4];
  if ((threadIdx.x & 63) == 0) red[threadIdx.x >> 6] = acc;
  __syncthreads();
  if (threadIdx.x == 0) u[s * B + b] = red[0] + red[1] + red[2] + red[3] + b2[0];
}

// ---------------- per-(b,slice): softmax, beta; slice of ctx + packing ----------------
__global__ __launch_bounds__(256) void softmax_ctx_pack(
    const float* __restrict__ u, const float* __restrict__ h,
    const float* __restrict__ ht, const float* __restrict__ beta_w,
    const float* __restrict__ beta_b, const float* __restrict__ emb,
    const int* __restrict__ Et, const unsigned long long* __restrict__ amax,
    ushort* __restrict__ xcat_hi, ushort* __restrict__ xcat_lo,
    ushort* __restrict__ cat2_hi, ushort* __restrict__ cat2_lo) {
  int b = blockIdx.x, slice = blockIdx.y, tid = threadIdx.x;
  __shared__ float a_sh[S];
  __shared__ float red[4];
  float uv = (tid < S) ? u[tid * B + b] : -INFINITY;
  float m = uv;
  for (int off = 32; off; off >>= 1) m = fmaxf(m, __shfl_xor(m, off));
  if ((tid & 63) == 0) red[tid >> 6] = m;
  __syncthreads();
  m = fmaxf(fmaxf(red[0], red[1]), fmaxf(red[2], red[3]));
  float e = (tid < S) ? expf(uv - m) : 0.f;
  float ssum = e;
  for (int off = 32; off; off >>= 1) ssum += __shfl_xor(ssum, off);
  __syncthreads();
  if ((tid & 63) == 0) red[tid >> 6] = ssum;
  __syncthreads();
  ssum = red[0] + red[1] + red[2] + red[3];
  if (tid < S) a_sh[tid] = e / ssum;
  float acc = 0.f;
  {
    const float4* h4 = (const float4*)(ht + (size_t)b * DD);
    const float4* w4 = (const float4*)beta_w;
    for (int i = tid; i < DD / 4; i += 256) {
      float4 x = h4[i], w = w4[i];
      acc += x.x * w.x + x.y * w.y + x.z * w.z + x.w * w.w;
    }
  }
  for (int off = 32; off; off >>= 1) acc += __shfl_xor(acc, off);
  __syncthreads();
  if ((tid & 63) == 0) red[tid >> 6] = acc;
  __syncthreads();
  float beta = sigf(red[0] + red[1] + red[2] + red[3] + beta_b[0]);

  const size_t xb = (size_t)b * KCP;
  for (int e0 = slice * 128 + tid; e0 < slice * 128 + 128; e0 += 256) {
    float c = 0.f;
    for (int si = 0; si < S; ++si) c += a_sh[si] * h[((size_t)si * B + b) * DENC + e0];
    c *= beta;
    ushort hh, ll; split1(c, hh, ll);
    xcat_hi[xb + DE + e0] = hh;      xcat_lo[xb + DE + e0] = ll;
    cat2_hi[xb + DD + DE + e0] = hh; cat2_lo[xb + DD + DE + e0] = ll;
  }
  int et = Et[b];
  int pt = (int)(~(unsigned)(amax[b] & 0xFFFFFFFFull));  // decoded argmax
  for (int e0 = slice * 128 + tid; e0 < slice * 128 + 128; e0 += 256) {
    ushort hh, ll;
    split1(emb[(size_t)et * DE + e0], hh, ll);
    xcat_hi[xb + e0] = hh; xcat_lo[xb + e0] = ll;
    split1(emb[(size_t)pt * DE + e0], hh, ll);
    cat2_hi[xb + DD + e0] = hh; cat2_lo[xb + DD + e0] = ll;
  }
  for (int j = slice * 450 + tid; j < slice * 450 + 450; j += 256) {
    ushort hh, ll; split1(ht[(size_t)b * DD + j], hh, ll);
    xcat_hi[xb + DE + DENC + j] = hh; xcat_lo[xb + DE + DENC + j] = ll;
  }
  if (slice == 3 && tid < KCP - KC) {
    xcat_hi[xb + KC + tid] = 0; xcat_lo[xb + KC + tid] = 0;
    cat2_hi[xb + KC + tid] = 0; cat2_lo[xb + KC + tid] = 0;
  }
}

// ---------------- LSTM: reduce gates partials + update + bf16 splits --------
__global__ __launch_bounds__(256) void lstm_fused(
    const float* __restrict__ P, int nz, const float* __restrict__ b_ih,
    const float* __restrict__ b_hh, float* __restrict__ ct, float* __restrict__ ht,
    ushort* __restrict__ cat2_hi, ushort* __restrict__ cat2_lo,
    ushort* __restrict__ ht_hi, ushort* __restrict__ ht_lo,
    unsigned long long* __restrict__ amax) {
  int idx = blockIdx.x * 256 + threadIdx.x;
  if (idx < B) amax[idx] = 0ull;
  if (idx >= B * DD) return;
  int b = idx / DD, d = idx % DD;
  const size_t MN = (size_t)B * G4;
  float g0 = 0.f, g1 = 0.f, g2 = 0.f, g3 = 0.f;
  for (int zz = 0; zz < nz; ++zz) {
    const float* g = P + (size_t)zz * MN + (size_t)b * G4;
    g0 += g[d]; g1 += g[DD + d]; g2 += g[2 * DD + d]; g3 += g[3 * DD + d];
  }
  g0 += b_ih[d] + b_hh[d];
  g1 += b_ih[DD + d] + b_hh[DD + d];
  g2 += b_ih[2 * DD + d] + b_hh[2 * DD + d];
  g3 += b_ih[3 * DD + d] + b_hh[3 * DD + d];
  float c = sigf(g1) * ct[idx] + sigf(g0) * tanhf(g2);
  float hn = sigf(g3) * tanhf(c);
  ct[idx] = c;
  ht[idx] = hn;
  ushort hh, ll; split1(hn, hh, ll);
  cat2_hi[(size_t)b * KCP + d] = hh; cat2_lo[(size_t)b * KCP + d] = ll;
  ht_hi[(size_t)b * DDP + d] = hh;   ht_lo[(size_t)b * DDP + d] = ll;
  if (d < DDP - DD) {
    ht_hi[(size_t)b * DDP + DD + d] = 0; ht_lo[(size_t)b * DDP + DD + d] = 0;
  }
}

// init: low32 = ~0 -> decodes to token 0
__global__ void init_amax(unsigned long long* amax) {
  if (threadIdx.x < B) amax[threadIdx.x] = 0x00000000FFFFFFFFull;
}

// ---- ws layout (float offsets): fp32 region | PBUF | ushort activations ----
constexpr size_t OFF_HAVG  = 0;
constexpr size_t OFF_TMP   = OFF_HAVG + 32768;
constexpr size_t OFF_HT    = OFF_TMP + 115200;
constexpr size_t OFF_CT    = OFF_HT + 115200;
constexpr size_t OFF_HPROJ = OFF_CT + 115200;         // 3136*1800
constexpr size_t OFF_Q     = OFF_HPROJ + 5644800;
constexpr size_t OFF_U     = OFF_Q + 115200;
constexpr size_t OFF_TOK   = OFF_U + 3200;            // 64 u64 = 128 floats
constexpr size_t OFF_PBUF  = OFF_TOK + 128;
constexpr size_t PBUF_F    = 6400000;                 // z=10 * B*V
constexpr size_t OFF_USH   = OFF_PBUF + PBUF_F;

// ushort offsets within ushort area (~58.5 MB total, proven to fit)
constexpr size_t U_HT_HI  = 0;
constexpr size_t U_HT_LO  = U_HT_HI + (size_t)B * DDP;
constexpr size_t U_XC_HI  = U_HT_LO + (size_t)B * DDP;
constexpr size_t U_XC_LO  = U_XC_HI + (size_t)B * KCP;
constexpr size_t U_C2_HI  = U_XC_LO + (size_t)B * KCP;
constexpr size_t U_C2_LO  = U_C2_HI + (size_t)B * KCP;
constexpr size_t U_H_HI   = U_C2_LO + (size_t)B * KCP;
constexpr size_t U_H_LO   = U_H_HI + (size_t)(S * B) * DENC;

}  // namespace

extern "C" void kernel_launch(void* const* d_in, const int* in_sizes, int n_in,
                              void* d_out, int out_size, void* d_ws, size_t ws_size,
                              hipStream_t stream) {
  const float* h       = (const float*)d_in[0];
  const int*   E       = (const int*)d_in[1];
  const float* emb     = (const float*)d_in[2];
  const float* attn_W1 = (const float*)d_in[3];
  const float* attn_b1 = (const float*)d_in[4];
  const float* attn_w2 = (const float*)d_in[5];
  const float* attn_b2 = (const float*)d_in[6];
  const float* beta_w  = (const float*)d_in[7];
  const float* beta_b  = (const float*)d_in[8];
  const float* W_ih    = (const float*)d_in[9];
  const float* W_hh    = (const float*)d_in[10];
  const float* b_ih    = (const float*)d_in[11];
  const float* b_hh    = (const float*)d_in[12];
  const float* out_W   = (const float*)d_in[13];
  const float* out_b   = (const float*)d_in[14];
  const float* ih_W1   = (const float*)d_in[15];
  const float* ih_b1   = (const float*)d_in[16];
  const float* ih_W2   = (const float*)d_in[17];
  const float* ih_b2   = (const float*)d_in[18];
  const float* ic_W1   = (const float*)d_in[19];
  const float* ic_b1   = (const float*)d_in[20];
  const float* ic_W2   = (const float*)d_in[21];
  const float* ic_b2   = (const float*)d_in[22];

  float* ws    = (float*)d_ws;
  float* havg  = ws + OFF_HAVG;
  float* tmp   = ws + OFF_TMP;
  float* ht    = ws + OFF_HT;
  float* ct    = ws + OFF_CT;
  float* Hproj = ws + OFF_HPROJ;
  float* Q     = ws + OFF_Q;
  float* u     = ws + OFF_U;
  unsigned long long* amax = (unsigned long long*)(ws + OFF_TOK);
  float* PBUF  = ws + OFF_PBUF;
  ushort* bfb  = (ushort*)(ws + OFF_USH);
  ushort* ht_hi = bfb + U_HT_HI;
  ushort* ht_lo = bfb + U_HT_LO;
  ushort* xc_hi = bfb + U_XC_HI;
  ushort* xc_lo = bfb + U_XC_LO;
  ushort* c2_hi = bfb + U_C2_HI;
  ushort* c2_lo = bfb + U_C2_LO;
  ushort* h_hi  = bfb + U_H_HI;
  ushort* h_lo  = bfb + U_H_LO;
  float* out   = (float*)d_out;

  // prologue scratch (reuses step-loop activation areas before first step)
  ushort* hv_hi = xc_hi;   // havg planes, KP=512
  ushort* hv_lo = xc_lo;
  ushort* t_hi  = c2_hi;   // tmp planes, KP=1824
  ushort* t_lo  = c2_lo;

  auto cdiv = [](int a, int b) { return (a + b - 1) / b; };
  const int BIGK = 1 << 28;

  // ---- prologue ----
  hmean_kernel<<<cdiv(B * DENC, 256), 256, 0, stream>>>(h, havg);
  split_row<<<B, 256, 0, stream>>>(havg, DENC, DENC, DENC, hv_hi, hv_lo);
  // h0: tmp = relu(havg @ ih_W1.T + b1); ht = tmp @ ih_W2.T + b2
  mfma_gemm9<<<dim3(cdiv(DD, 128), 1, 4), 256, 0, stream>>>(
      hv_hi, hv_lo, DENC, ih_W1, DENC, BIGK, ih_W1, DENC, DENC,
      PBUF, B, DD, DENC, 128, nullptr);
  reduce_k<1><<<cdiv(B * DD / 4, 256), 256, 0, stream>>>(
      PBUF, 4, B * DD / 4, (size_t)B * DD, DD, ih_b1, tmp);
  split_row<<<B, 256, 0, stream>>>(tmp, DD, DD, DDP, t_hi, t_lo);
  mfma_gemm9<<<dim3(cdiv(DD, 128), 1, 12), 256, 0, stream>>>(
      t_hi, t_lo, DDP, ih_W2, DD, BIGK, ih_W2, DD, DD,
      PBUF, B, DD, DDP, 160, nullptr);
  reduce_k<0><<<cdiv(B * DD / 4, 256), 256, 0, stream>>>(
      PBUF, 12, B * DD / 4, (size_t)B * DD, DD, ih_b2, ht);
  // c0
  mfma_gemm9<<<dim3(cdiv(DD, 128), 1, 4), 256, 0, stream>>>(
      hv_hi, hv_lo, DENC, ic_W1, DENC, BIGK, ic_W1, DENC, DENC,
      PBUF, B, DD, DENC, 128, nullptr);
  reduce_k<1><<<cdiv(B * DD / 4, 256), 256, 0, stream>>>(
      PBUF, 4, B * DD / 4, (size_t)B * DD, DD, ic_b1, tmp);
  split_row<<<B, 256, 0, stream>>>(tmp, DD, DD, DDP, t_hi, t_lo);
  mfma_gemm9<<<dim3(cdiv(DD, 128), 1, 12), 256, 0, stream>>>(
      t_hi, t_lo, DDP, ic_W2, DD, BIGK, ic_W2, DD, DD,
      PBUF, B, DD, DDP, 160, nullptr);
  reduce_k<0><<<cdiv(B * DD / 4, 256), 256, 0, stream>>>(
      PBUF, 12, B * DD / 4, (size_t)B * DD, DD, ic_b2, ct);
  // splits for step loop
  split_row<<<B, 256, 0, stream>>>(ht, DD, DD, DDP, ht_hi, ht_lo);
  split_row<<<S * B, 256, 0, stream>>>(h, DENC, DENC, DENC, h_hi, h_lo);
  // Hproj = h @ W1h.T + attn_b1  (z=1, kchunk=512, bias fused in epilogue)
  mfma_gemm9<<<dim3(cdiv(DD, 128), S * B / 64, 1), 256, 0, stream>>>(
      h_hi, h_lo, DENC, attn_W1 + DD, DD + DENC, BIGK, attn_W1 + DD,
      DD + DENC, DENC, Hproj, S * B, DD, DENC, 512, attn_b1);
  init_amax<<<1, 64, 0, stream>>>(amax);

  // ---- decode steps ----
  for (int t = 0; t < T - 1; ++t) {
    // Q = ht @ W1q.T  (z=12, kchunk=160)
    mfma_gemm9<<<dim3(cdiv(DD, 128), 1, 12), 256, 0, stream>>>(
        ht_hi, ht_lo, DDP, attn_W1, DD + DENC, BIGK, attn_W1, DD + DENC, DD,
        PBUF, B, DD, DDP, 160, nullptr);
    reduce_k<0><<<cdiv(B * DD / 4, 256), 256, 0, stream>>>(
        PBUF, 12, B * DD / 4, (size_t)B * DD, DD, nullptr, Q);
    attn_u_kernel<<<dim3(S, B), 256, 0, stream>>>(Q, Hproj, attn_w2, attn_b2, u);
    softmax_ctx_pack<<<dim3(B, 4), 256, 0, stream>>>(u, h, ht, beta_w, beta_b, emb,
        E + (size_t)t * B, amax, xc_hi, xc_lo, c2_hi, c2_lo);
    // gates = xcat @ [W_ih | W_hh].T  (z=12, kchunk=256)
    mfma_gemm9<<<dim3(cdiv(G4, 128), 1, 12), 256, 0, stream>>>(
        xc_hi, xc_lo, KCP, W_ih, DE + DENC, DE + DENC, W_hh, DD, KC,
        PBUF, B, G4, KCP, 256, nullptr);
    lstm_fused<<<cdiv(B * DD, 256), 256, 0, stream>>>(
        PBUF, 12, b_ih, b_hh, ct, ht, c2_hi, c2_lo, ht_hi, ht_lo, amax);
    // logits = cat2 @ out_W.T  (z=10, kchunk=288) -> d_out[t], fused argmax
    float* logits_t = out + (size_t)t * B * V;
    mfma_gemm9<<<dim3(cdiv(V, 128), 1, 10), 256, 0, stream>>>(
        c2_hi, c2_lo, KCP, out_W, KC, BIGK, out_W, KC, KC,
        PBUF, B, V, KCP, 288, nullptr);
    reduce_lg<<<dim3(10, B), 256, 0, stream>>>(PBUF, 10, out_b, logits_t, amax);
  }
  (void)in_sizes; (void)n_in; (void)out_size; (void)ws_size;
}